// Round 13
// baseline (6151.907 us; speedup 1.0000x reference)
//
#include <hip/hip_runtime.h>
#include <stdint.h>

typedef __bf16 bf16;
typedef __attribute__((ext_vector_type(8))) __bf16 bf16x8;
typedef __attribute__((ext_vector_type(4))) float f32x4;
typedef __attribute__((ext_vector_type(4))) unsigned u32x4;

// ---------------- workspace layout (bytes) — byte-identical to R1/R6/R8/R10/R12 ----------------
#define OFF_W0P   0ull
#define SZ_W0P    10485760ull
#define OFF_W1P   (OFF_W0P + SZ_W0P)
#define SZ_W1P    16777216ull
#define OFF_WOUT  (OFF_W1P + SZ_W1P)
#define SZ_WOUT   524288ull
#define OFF_B0P   (OFF_WOUT + SZ_WOUT)      // f32 permuted b0 [4096]
#define OFF_B1P   (OFF_B0P + 16384ull)      // f32 permuted b1 [4096]
#define OFF_BOP   (OFF_B1P + 16384ull)      // f32 bout [256]
#define OFF_BAR   (OFF_BOP + 1024ull)       // (legacy, unused)
#define OFF_FLAG  (OFF_BAR + 128ull)        // dtype flag: 1 = inputs are f32, 0 = bf16
#define OFF_H0PP  (OFF_BAR + 256ull)        // h0 ping-pong: 2 x 131072 (A-frag packed bf16)
#define OFF_H1PP  (OFF_H0PP + 262144ull)    // h1 ping-pong: 2 x 131072
#define OFF_XP    (OFF_H1PP + 262144ull)
#define SZ_XP     16777216ull
#define OFF_FLAGS (OFF_XP + SZ_XP)          // 256 x u32 arrival flags (1 KB)
#define OFF_REL   (OFF_FLAGS + 1024ull)     // release word
// end = 45,123,968 bytes

#define OUT_FS0   8388608
#define OUT_FS1   8519680

// LDS: B0 [0,40960); B1 [40960,106496); outproj partials [106496,110592)
#define LDS_PARTP 106496
#define LDS_TOTAL 110592

// cachepolicy sc0|sc1: device-coherent write-through for h STORES (L3 always fresh, no wbl2).
#define CPOL_CC 17

typedef const __attribute__((address_space(1))) void gvoid_t;
typedef __attribute__((address_space(3))) void lvoid_t;

__device__ __forceinline__ void gl_lds16(void* lds, const void* g) {
  __builtin_amdgcn_global_load_lds((gvoid_t*)g, (lvoid_t*)lds, 16, 0, 0);
}

__device__ __forceinline__ __amdgpu_buffer_rsrc_t make_rsrc(const void* p) {
  return __builtin_amdgcn_make_buffer_rsrc(const_cast<void*>(p), (short)0, 0xFFFFFFFFu, 0x00020000u);
}

__device__ __forceinline__ void st_h2(__amdgpu_buffer_rsrc_t rs, unsigned off, float h) {
  bf16 b = (bf16)h;
  __builtin_amdgcn_raw_buffer_store_b16(__builtin_bit_cast(unsigned short, b), rs, off, 0, CPOL_CC);
}

// packed A-fragment byte offset for h buffers: element (batch b, unit u)
__device__ __forceinline__ size_t hpack_off(int b, int u) {
  return (size_t)((((b >> 4) * 32 + (u >> 5)) * 64 + ((b & 15) | (((u >> 3) & 3) << 4))) * 16 + ((u & 7) << 1));
}

__device__ __forceinline__ float sigm(float v) { return 1.0f / (1.0f + __expf(-v)); }
__device__ __forceinline__ float tanh_(float v) { return 2.0f / (1.0f + __expf(-2.0f * v)) - 1.0f; }
__device__ __forceinline__ float scrub(float v, float lim) { return fminf(fmaxf(v, -lim), lim); }

__device__ __forceinline__ float ldel(const void* p, size_t i, int fl) {
  return fl ? ((const float*)p)[i] : (float)((const bf16*)p)[i];
}

// ---------------- dtype detection ----------------
__global__ __launch_bounds__(256) void detect_kernel(const void* __restrict__ W0, char* __restrict__ ws) {
  __shared__ int cnt;
  if (threadIdx.x == 0) cnt = 0;
  __syncthreads();
  int local = 0;
  const unsigned* w = (const unsigned*)W0;
#pragma unroll
  for (int i = 0; i < 4; ++i) {
    unsigned e = (w[threadIdx.x * 4 + i] >> 7) & 0xFF;
    local += (e >= 0x68 && e <= 0x7E) ? 1 : 0;
  }
  atomicAdd(&cnt, local);
  __syncthreads();
  if (threadIdx.x == 0) *(unsigned*)(ws + OFF_FLAG) = (cnt < 512) ? 1u : 0u;
}

// ---------------- weight/x prep (unchanged layouts) ----------------
__global__ __launch_bounds__(256) void prep_pack(const void* __restrict__ x, const void* __restrict__ W0,
                                                 const void* __restrict__ b0, const void* __restrict__ W1,
                                                 const void* __restrict__ b1, const void* __restrict__ Wout,
                                                 const void* __restrict__ bout, char* __restrict__ ws) {
  const int fl = *(const unsigned*)(ws + OFF_FLAG);
  int id = blockIdx.x * 256 + threadIdx.x;
  if (id < 5242880) {                                    // W0P
    int tile = id / 20480, rem = id % 20480;
    int kt = rem >> 9, l = (rem >> 3) & 63, jj = rem & 7;
    int k = kt * 32 + ((l >> 4) << 3) + jj;
    int pc = tile * 16 + (l & 15);
    ((bf16*)(ws + OFF_W0P))[id] = (bf16)ldel(W0, (size_t)k * 4096 + (pc & 3) * 1024 + (pc >> 2), fl);
  } else if (id < 13631488) {                            // W1P
    int id2 = id - 5242880;
    int tile = id2 >> 15, rem = id2 & 32767;
    int kt = rem >> 9, l = (rem >> 3) & 63, jj = rem & 7;
    int k = kt * 32 + ((l >> 4) << 3) + jj;
    int pc = tile * 16 + (l & 15);
    ((bf16*)(ws + OFF_W1P))[id2] = (bf16)ldel(W1, (size_t)k * 4096 + (pc & 3) * 1024 + (pc >> 2), fl);
  } else if (id < 13893632) {                            // WOUT
    int id2 = id - 13631488;
    int kt = id2 / 8192, rem = id2 % 8192;
    int nt = rem >> 9, l = (rem >> 3) & 63, jj = rem & 7;
    ((bf16*)(ws + OFF_WOUT))[id2] = (bf16)ldel(Wout, (size_t)(kt * 32 + ((l >> 4) << 3) + jj) * 256 + nt * 16 + (l & 15), fl);
  } else if (id < 13897728) {                            // b0 permuted -> f32
    int pc = id - 13893632;
    ((float*)(ws + OFF_B0P))[pc] = ldel(b0, (pc & 3) * 1024 + (pc >> 2), fl);
  } else if (id < 13901824) {                            // b1 permuted -> f32
    int pc = id - 13897728;
    ((float*)(ws + OFF_B1P))[pc] = ldel(b1, (pc & 3) * 1024 + (pc >> 2), fl);
  } else if (id < 13902080) {                            // bout -> f32
    int pc = id - 13901824;
    ((float*)(ws + OFF_BOP))[pc] = ldel(bout, pc, fl);
  } else if (id < 22290688) {                            // XP
    int id2 = id - 13902080;
    int t = id2 >> 14, rem = id2 & 16383;
    int mt = rem >> 12, rem2 = rem & 4095;
    int kt = rem2 >> 9, l = (rem2 >> 3) & 63, j = rem2 & 7;
    int b = mt * 16 + (l & 15);
    int v = kt * 32 + ((l >> 4) << 3) + j;
    ((bf16*)(ws + OFF_XP))[id2] = (bf16)ldel(x, ((size_t)b * 512 + t) * 256 + v, fl);
  }
}

// ---------------- initial h states + zero barrier flags ----------------
__global__ __launch_bounds__(256) void init_state(const void* __restrict__ s0, const void* __restrict__ s1,
                                                  char* __restrict__ ws) {
  const int fl = *(const unsigned*)(ws + OFF_FLAG);
  int id = blockIdx.x * 256 + threadIdx.x;
  if (id < 65536) {
    int b = id >> 10, u = id & 1023;
    *(bf16*)(ws + OFF_H0PP + 131072 + hpack_off(b, u)) = (bf16)ldel(s0, b * 2048 + 1024 + u, fl);  // h0(-1) -> slot 1
  } else if (id < 131072) {
    int id2 = id - 65536; int b = id2 >> 10, u = id2 & 1023;
    *(bf16*)(ws + OFF_H1PP + hpack_off(b, u)) = (bf16)ldel(s1, b * 2048 + 1024 + u, fl);           // h1(-1) -> slot 0
  } else if (id < 131330) {
    ((unsigned*)(ws + OFF_FLAGS))[id - 131072] = 0u;   // 256 flags + release word
  }
}

// ---------------- persistent kernel: recurrence + fused output projection ----------------
// R12 baseline (4804 us) + two serial-chain cuts:
//  (1) s_sleep(8) -> s_sleep(4) on both polls (wake-up quantization 512 -> 256 cycles).
//  (2) outproj finish (reduce + out stores) moved AFTER the arrival-flag store, executed by
//      wid==1 (NOT wid0 — tid0 runs the release poll; R11's mistake was loading tid0's path).
//      Partials are LDS-visible via the drain-__syncthreads; the dedicated p==3 barrier is
//      removed. The out stores drain under the NEXT iteration's vmcnt (overlap the poll).
// Coherence protocol unchanged: sc1 write-through h stores + cached h loads + inv-only acquire.
__global__ __launch_bounds__(256, 1) void recur_kernel(const void* __restrict__ s0, const void* __restrict__ s1,
                                                       char* __restrict__ ws, void* __restrict__ outv) {
  extern __shared__ char smem[];
  const int fl = *(const unsigned*)(ws + OFF_FLAG);
  const int tid = threadIdx.x;
  const int lane = tid & 63;
  const int wid = tid >> 6;
  const int cu = blockIdx.x;
  const int nt = cu & 15, mo = (cu >> 4) & 3, dg = cu >> 6;

  auto store_out = [&](size_t idx, float v) {
    if (fl) ((float*)outv)[idx] = v; else ((bf16*)outv)[idx] = (bf16)v;
  };

  // ---- B preload (once) ----
  {
    const char* g0 = ws + OFF_W0P + (size_t)cu * 40960;
    for (int off = tid * 16; off < 40960; off += 4096) gl_lds16(smem + off, g0 + off);
    const char* g1 = ws + OFF_W1P + (size_t)cu * 65536;
    for (int off = tid * 16; off < 65536; off += 4096) gl_lds16(smem + 40960 + off, g1 + off);
  }
  // ---- Wout B-frags in registers ----
  bf16x8 wreg[8];
#pragma unroll
  for (int i = 0; i < 8; ++i)
    wreg[i] = *(const bf16x8*)(ws + OFF_WOUT + (size_t)(((wid * 8 + i) * 16 + nt) * 64 + lane) * 16);

  const float bini0 = ((const float*)(ws + OFF_B0P))[cu * 16 + (lane & 15)];
  const float bini1 = ((const float*)(ws + OFF_B1P))[cu * 16 + (lane & 15)];
  const float boN = ((const float*)(ws + OFF_BOP))[nt * 16 + (lane & 15)];
  const int u0 = cu * 4 + ((lane & 15) >> 2);
  float c0reg[4], c1reg[4];
#pragma unroll
  for (int r = 0; r < 4; ++r) {
    int b = wid * 16 + ((lane >> 4) << 2) + r;
    c0reg[r] = ldel(s0, b * 2048 + u0, fl);
    c1reg[r] = ldel(s1, b * 2048 + u0, fl);
  }

  const __amdgpu_buffer_rsrc_t rs = make_rsrc(ws);     // for write-through h stores only
  unsigned* flags = (unsigned*)(ws + OFF_FLAGS);
  unsigned* rel   = (unsigned*)(ws + OFF_REL);
  const char* dummy = ws + (size_t)lane * 16;          // always-valid bf16
  const char* lb0 = smem + (size_t)lane * 16;          // B0 frag base (+ s*1024 imm)
  const char* lb1 = smem + 40960 + (size_t)lane * 16;  // B1 frag base (+ (s-8)*1024 imm)

  __syncthreads();  // B preload landed

  // persistent outproj window state
  bf16x8 pf0, pf1, pf2, pf3, pf4, pf5, pf6, pf7;
  f32x4 accP;

  for (int it = 0; it < 517; ++it) {
    const bool a0 = (it < 512);
    const bool a1 = (it >= 1 && it <= 512);
    const bool last = (it == 516);
    const int p = (it - 2 - dg) & 3;
    const int tP = it - 2 - p;
    const bool pw = (it >= 2 && tP >= 0 && tP <= 511);
    const char* h0src = ws + OFF_H0PP + (size_t)((it + 1) & 1) * 131072;   // h0(it-1)
    const char* h1src = ws + OFF_H1PP + (size_t)((it + 1) & 1) * 131072;   // h1(it-2)

    const char* ph0 = (it <= 512) ? (h0src + (size_t)(wid * 32) * 1024 + (size_t)lane * 16) : dummy;
    const char* ph1 = a1 ? (h1src + (size_t)(wid * 32) * 1024 + (size_t)lane * 16) : dummy;

    // ---- p==0: load the window's 8 pf frags of h1(tP) into persistent regs (cached loads) ----
    if (pw && p == 0) {
      const char* pm = h1src + (size_t)(mo * 32 + wid * 8) * 1024 + (size_t)lane * 16;
      pf0 = *(const bf16x8*)(pm);
      pf1 = *(const bf16x8*)(pm + 1024);
      pf2 = *(const bf16x8*)(pm + 2048);
      pf3 = *(const bf16x8*)(pm + 3072);
      pf4 = *(const bf16x8*)(pm + 4096);
      pf5 = *(const bf16x8*)(pm + 5120);
      pf6 = *(const bf16x8*)(pm + 6144);
      pf7 = *(const bf16x8*)(pm + 7168);
#pragma unroll
      for (int r = 0; r < 4; ++r) accP[r] = 0.f;
    }

    f32x4 acc0, acc1;
#pragma unroll
    for (int r = 0; r < 4; ++r) { acc0[r] = bini0; acc1[r] = bini1; }

    if (it < 514) {
      const char* px = a0 ? (ws + OFF_XP + (size_t)((it * 4 + wid) * 8) * 1024 + (size_t)lane * 16) : dummy;

      // ---- register-ring streamed GEMM (24-deep, cached loads): 0..7=x, 8..39=h0, 40..71=h1 ----
      bf16x8 ring[24];
#pragma unroll
      for (int s = 0; s < 24; ++s)
        ring[s] = *(const bf16x8*)(s < 8 ? px + s * 1024 : ph0 + (s - 8) * 1024);
#pragma unroll
      for (int s = 0; s < 72; ++s) {
        bf16x8 af = ring[s % 24];
        const int f = s + 24;
        if (f < 72)
          ring[s % 24] = *(const bf16x8*)(f < 40 ? ph0 + (f - 8) * 1024 : ph1 + (f - 40) * 1024);
        if (s < 40)
          acc0 = __builtin_amdgcn_mfma_f32_16x16x32_bf16(af, *(const bf16x8*)(lb0 + s * 1024), acc0, 0, 0, 0);
        if (s >= 8)
          acc1 = __builtin_amdgcn_mfma_f32_16x16x32_bf16(af, *(const bf16x8*)(lb1 + (s - 8) * 1024), acc1, 0, 0, 0);
      }
    }

    // ---- 2 outproj MFMAs per iteration (uniform) ----
    if (pw) {
      switch (p) {
        case 0:
          accP = __builtin_amdgcn_mfma_f32_16x16x32_bf16(pf0, wreg[0], accP, 0, 0, 0);
          accP = __builtin_amdgcn_mfma_f32_16x16x32_bf16(pf1, wreg[1], accP, 0, 0, 0);
          break;
        case 1:
          accP = __builtin_amdgcn_mfma_f32_16x16x32_bf16(pf2, wreg[2], accP, 0, 0, 0);
          accP = __builtin_amdgcn_mfma_f32_16x16x32_bf16(pf3, wreg[3], accP, 0, 0, 0);
          break;
        case 2:
          accP = __builtin_amdgcn_mfma_f32_16x16x32_bf16(pf4, wreg[4], accP, 0, 0, 0);
          accP = __builtin_amdgcn_mfma_f32_16x16x32_bf16(pf5, wreg[5], accP, 0, 0, 0);
          break;
        default:
          accP = __builtin_amdgcn_mfma_f32_16x16x32_bf16(pf6, wreg[6], accP, 0, 0, 0);
          accP = __builtin_amdgcn_mfma_f32_16x16x32_bf16(pf7, wreg[7], accP, 0, 0, 0);
          break;
      }
    }

    // ---- LSTM epilogues (h stores: sc1 write-through) ----
    const int base = lane & 60;
    if (a0) {
      const unsigned h0w = (unsigned)(OFF_H0PP) + (unsigned)(it & 1) * 131072u;
#pragma unroll
      for (int r = 0; r < 4; ++r) {
        float z = acc0[r];
        float zi = scrub(__shfl(z, base + 0, 64), 80.f);
        float zj = scrub(__shfl(z, base + 1, 64), 80.f);
        float zf = scrub(__shfl(z, base + 2, 64), 80.f);
        float zo = scrub(__shfl(z, base + 3, 64), 80.f);
        float c = c0reg[r];
        c = c * sigm(zf + 1.0f) + sigm(zi) * tanh_(zj);
        c = scrub(c, 1000.f);
        float h = tanh_(c) * sigm(zo);
        c0reg[r] = c;
        if ((lane & 3) == 0) {
          int b = wid * 16 + ((lane >> 4) << 2) + r;
          st_h2(rs, h0w + (unsigned)hpack_off(b, u0), h);
          if (it == 511) { store_out(OUT_FS0 + b * 2048 + u0, c); store_out(OUT_FS0 + b * 2048 + 1024 + u0, h); }
        }
      }
    }
    if (a1) {
      const unsigned h1w = (unsigned)(OFF_H1PP) + (unsigned)(it & 1) * 131072u;
#pragma unroll
      for (int r = 0; r < 4; ++r) {
        float z = acc1[r];
        float zi = scrub(__shfl(z, base + 0, 64), 80.f);
        float zj = scrub(__shfl(z, base + 1, 64), 80.f);
        float zf = scrub(__shfl(z, base + 2, 64), 80.f);
        float zo = scrub(__shfl(z, base + 3, 64), 80.f);
        float c = c1reg[r];
        c = c * sigm(zf + 1.0f) + sigm(zi) * tanh_(zj);
        c = scrub(c, 1000.f);
        float h = tanh_(c) * sigm(zo);
        c1reg[r] = c;
        if ((lane & 3) == 0) {
          int b = wid * 16 + ((lane >> 4) << 2) + r;
          st_h2(rs, h1w + (unsigned)hpack_off(b, u0), h);
          if (it == 512) { store_out(OUT_FS1 + b * 2048 + u0, c); store_out(OUT_FS1 + b * 2048 + 1024 + u0, h); }
        }
      }
    }

    // ---- outproj partials to LDS (finish happens after arrival, by wid1) ----
    if (pw && p == 3)
      *(f32x4*)(smem + LDS_PARTP + (size_t)(wid * 64 + lane) * 16) = accP;

    if (last) {
      // no barrier after the final iteration; finish inline (partials need a sync)
      if (pw && p == 3) {
        __syncthreads();
        if (wid == 0) {
          f32x4 sm = *(const f32x4*)(smem + LDS_PARTP + (size_t)lane * 16);
#pragma unroll
          for (int w = 1; w < 4; ++w) {
            f32x4 q = *(const f32x4*)(smem + LDS_PARTP + (size_t)(w * 64 + lane) * 16);
#pragma unroll
            for (int r = 0; r < 4; ++r) sm[r] += q[r];
          }
#pragma unroll
          for (int r = 0; r < 4; ++r) {
            int b = mo * 16 + ((lane >> 4) << 2) + r;
            store_out(((size_t)b * 512 + tP) * 256 + nt * 16 + (lane & 15), sm[r] + boN);
          }
        }
      }
      break;
    }

    // ---- barrier: drain h stores -> arrive -> (wid1: outproj finish) -> CU0 agg -> release -> inv ----
    asm volatile("s_waitcnt vmcnt(0)" ::: "memory");   // h stores ack'd at coherence point
    __syncthreads();                                   // also makes LDS partials visible
    if (tid == 0)
      __hip_atomic_store(flags + cu, (unsigned)(it + 1), __ATOMIC_RELAXED, __HIP_MEMORY_SCOPE_AGENT);

    // outproj finish overlaps the barrier wait; wid1 (NOT the polling tid0's wave) does it
    if (pw && p == 3 && wid == 1) {
      f32x4 sm = *(const f32x4*)(smem + LDS_PARTP + (size_t)lane * 16);
#pragma unroll
      for (int w = 1; w < 4; ++w) {
        f32x4 q = *(const f32x4*)(smem + LDS_PARTP + (size_t)(w * 64 + lane) * 16);
#pragma unroll
        for (int r = 0; r < 4; ++r) sm[r] += q[r];
      }
#pragma unroll
      for (int r = 0; r < 4; ++r) {
        int b = mo * 16 + ((lane >> 4) << 2) + r;
        store_out(((size_t)b * 512 + tP) * 256 + nt * 16 + (lane & 15), sm[r] + boN);
      }
    }

    if (cu == 0) {
      while (__hip_atomic_load(flags + tid, __ATOMIC_RELAXED, __HIP_MEMORY_SCOPE_AGENT) < (unsigned)(it + 1))
        __builtin_amdgcn_s_sleep(4);
      __syncthreads();
      if (tid == 0)
        __hip_atomic_store(rel, (unsigned)(it + 1), __ATOMIC_RELAXED, __HIP_MEMORY_SCOPE_AGENT);
    }
    if (tid == 0) {
      while (__hip_atomic_load(rel, __ATOMIC_RELAXED, __HIP_MEMORY_SCOPE_AGENT) < (unsigned)(it + 1))
        __builtin_amdgcn_s_sleep(4);
      __builtin_amdgcn_fence(__ATOMIC_ACQUIRE, "agent");   // inv L1/L2: evict stale h lines
    }
    __syncthreads();
  }
}

extern "C" void kernel_launch(void* const* d_in, const int* in_sizes, int n_in,
                              void* d_out, int out_size, void* d_ws, size_t ws_size,
                              hipStream_t stream) {
  const void* x    = d_in[0];
  const void* s0   = d_in[1];
  const void* s1   = d_in[2];
  const void* W0   = d_in[3];
  const void* b0   = d_in[4];
  const void* W1   = d_in[5];
  const void* b1   = d_in[6];
  const void* Wout = d_in[7];
  const void* bout = d_in[8];
  char* ws = (char*)d_ws;
  (void)in_sizes; (void)n_in; (void)out_size; (void)ws_size;

  hipFuncSetAttribute((const void*)recur_kernel, hipFuncAttributeMaxDynamicSharedMemorySize, LDS_TOTAL);

  hipLaunchKernelGGL(detect_kernel, dim3(1),     dim3(256), 0, stream, W0, ws);
  hipLaunchKernelGGL(prep_pack,     dim3(87073), dim3(256), 0, stream, x, W0, b0, W1, b1, Wout, bout, ws);
  hipLaunchKernelGGL(init_state,    dim3(514),   dim3(256), 0, stream, s0, s1, ws);
  hipLaunchKernelGGL(recur_kernel,  dim3(256),   dim3(256), LDS_TOTAL, stream, s0, s1, ws, d_out);
}

// Round 14
// 4801.944 us; speedup vs baseline: 1.2811x; 1.2811x over previous
//
#include <hip/hip_runtime.h>
#include <stdint.h>

typedef __bf16 bf16;
typedef __attribute__((ext_vector_type(8))) __bf16 bf16x8;
typedef __attribute__((ext_vector_type(4))) float f32x4;
typedef __attribute__((ext_vector_type(4))) unsigned u32x4;

// ---------------- workspace layout (bytes) — byte-identical to R1/R6/R8/R10/R12 ----------------
#define OFF_W0P   0ull
#define SZ_W0P    10485760ull
#define OFF_W1P   (OFF_W0P + SZ_W0P)
#define SZ_W1P    16777216ull
#define OFF_WOUT  (OFF_W1P + SZ_W1P)
#define SZ_WOUT   524288ull
#define OFF_B0P   (OFF_WOUT + SZ_WOUT)      // f32 permuted b0 [4096]
#define OFF_B1P   (OFF_B0P + 16384ull)      // f32 permuted b1 [4096]
#define OFF_BOP   (OFF_B1P + 16384ull)      // f32 bout [256]
#define OFF_BAR   (OFF_BOP + 1024ull)       // (legacy, unused)
#define OFF_FLAG  (OFF_BAR + 128ull)        // dtype flag: 1 = inputs are f32, 0 = bf16
#define OFF_H0PP  (OFF_BAR + 256ull)        // h0 ping-pong: 2 x 131072 (A-frag packed bf16)
#define OFF_H1PP  (OFF_H0PP + 262144ull)    // h1 ping-pong: 2 x 131072
#define OFF_XP    (OFF_H1PP + 262144ull)
#define SZ_XP     16777216ull
#define OFF_FLAGS (OFF_XP + SZ_XP)          // 256 x u32 arrival flags (1 KB)
#define OFF_REL   (OFF_FLAGS + 1024ull)     // release word
// end = 45,123,968 bytes

#define OUT_FS0   8388608
#define OUT_FS1   8519680

// LDS: B0 [0,40960); B1 [40960,106496); outproj partials [106496,110592)
#define LDS_PARTP 106496
#define LDS_TOTAL 110592

// cachepolicy sc0|sc1: device-coherent write-through for h STORES (L3 always fresh, no wbl2).
#define CPOL_CC 17

typedef const __attribute__((address_space(1))) void gvoid_t;
typedef __attribute__((address_space(3))) void lvoid_t;

__device__ __forceinline__ void gl_lds16(void* lds, const void* g) {
  __builtin_amdgcn_global_load_lds((gvoid_t*)g, (lvoid_t*)lds, 16, 0, 0);
}

__device__ __forceinline__ __amdgpu_buffer_rsrc_t make_rsrc(const void* p) {
  return __builtin_amdgcn_make_buffer_rsrc(const_cast<void*>(p), (short)0, 0xFFFFFFFFu, 0x00020000u);
}

__device__ __forceinline__ void st_h2(__amdgpu_buffer_rsrc_t rs, unsigned off, float h) {
  bf16 b = (bf16)h;
  __builtin_amdgcn_raw_buffer_store_b16(__builtin_bit_cast(unsigned short, b), rs, off, 0, CPOL_CC);
}

// packed A-fragment byte offset for h buffers: element (batch b, unit u)
__device__ __forceinline__ size_t hpack_off(int b, int u) {
  return (size_t)((((b >> 4) * 32 + (u >> 5)) * 64 + ((b & 15) | (((u >> 3) & 3) << 4))) * 16 + ((u & 7) << 1));
}

__device__ __forceinline__ float sigm(float v) { return 1.0f / (1.0f + __expf(-v)); }
__device__ __forceinline__ float tanh_(float v) { return 2.0f / (1.0f + __expf(-2.0f * v)) - 1.0f; }
__device__ __forceinline__ float scrub(float v, float lim) { return fminf(fmaxf(v, -lim), lim); }

__device__ __forceinline__ float ldel(const void* p, size_t i, int fl) {
  return fl ? ((const float*)p)[i] : (float)((const bf16*)p)[i];
}

// ---------------- dtype detection ----------------
__global__ __launch_bounds__(256) void detect_kernel(const void* __restrict__ W0, char* __restrict__ ws) {
  __shared__ int cnt;
  if (threadIdx.x == 0) cnt = 0;
  __syncthreads();
  int local = 0;
  const unsigned* w = (const unsigned*)W0;
#pragma unroll
  for (int i = 0; i < 4; ++i) {
    unsigned e = (w[threadIdx.x * 4 + i] >> 7) & 0xFF;
    local += (e >= 0x68 && e <= 0x7E) ? 1 : 0;
  }
  atomicAdd(&cnt, local);
  __syncthreads();
  if (threadIdx.x == 0) *(unsigned*)(ws + OFF_FLAG) = (cnt < 512) ? 1u : 0u;
}

// ---------------- weight/x prep (unchanged layouts) ----------------
__global__ __launch_bounds__(256) void prep_pack(const void* __restrict__ x, const void* __restrict__ W0,
                                                 const void* __restrict__ b0, const void* __restrict__ W1,
                                                 const void* __restrict__ b1, const void* __restrict__ Wout,
                                                 const void* __restrict__ bout, char* __restrict__ ws) {
  const int fl = *(const unsigned*)(ws + OFF_FLAG);
  int id = blockIdx.x * 256 + threadIdx.x;
  if (id < 5242880) {                                    // W0P
    int tile = id / 20480, rem = id % 20480;
    int kt = rem >> 9, l = (rem >> 3) & 63, jj = rem & 7;
    int k = kt * 32 + ((l >> 4) << 3) + jj;
    int pc = tile * 16 + (l & 15);
    ((bf16*)(ws + OFF_W0P))[id] = (bf16)ldel(W0, (size_t)k * 4096 + (pc & 3) * 1024 + (pc >> 2), fl);
  } else if (id < 13631488) {                            // W1P
    int id2 = id - 5242880;
    int tile = id2 >> 15, rem = id2 & 32767;
    int kt = rem >> 9, l = (rem >> 3) & 63, jj = rem & 7;
    int k = kt * 32 + ((l >> 4) << 3) + jj;
    int pc = tile * 16 + (l & 15);
    ((bf16*)(ws + OFF_W1P))[id2] = (bf16)ldel(W1, (size_t)k * 4096 + (pc & 3) * 1024 + (pc >> 2), fl);
  } else if (id < 13893632) {                            // WOUT
    int id2 = id - 13631488;
    int kt = id2 / 8192, rem = id2 % 8192;
    int nt = rem >> 9, l = (rem >> 3) & 63, jj = rem & 7;
    ((bf16*)(ws + OFF_WOUT))[id2] = (bf16)ldel(Wout, (size_t)(kt * 32 + ((l >> 4) << 3) + jj) * 256 + nt * 16 + (l & 15), fl);
  } else if (id < 13897728) {                            // b0 permuted -> f32
    int pc = id - 13893632;
    ((float*)(ws + OFF_B0P))[pc] = ldel(b0, (pc & 3) * 1024 + (pc >> 2), fl);
  } else if (id < 13901824) {                            // b1 permuted -> f32
    int pc = id - 13897728;
    ((float*)(ws + OFF_B1P))[pc] = ldel(b1, (pc & 3) * 1024 + (pc >> 2), fl);
  } else if (id < 13902080) {                            // bout -> f32
    int pc = id - 13901824;
    ((float*)(ws + OFF_BOP))[pc] = ldel(bout, pc, fl);
  } else if (id < 22290688) {                            // XP
    int id2 = id - 13902080;
    int t = id2 >> 14, rem = id2 & 16383;
    int mt = rem >> 12, rem2 = rem & 4095;
    int kt = rem2 >> 9, l = (rem2 >> 3) & 63, j = rem2 & 7;
    int b = mt * 16 + (l & 15);
    int v = kt * 32 + ((l >> 4) << 3) + j;
    ((bf16*)(ws + OFF_XP))[id2] = (bf16)ldel(x, ((size_t)b * 512 + t) * 256 + v, fl);
  }
}

// ---------------- initial h states + zero barrier flags ----------------
__global__ __launch_bounds__(256) void init_state(const void* __restrict__ s0, const void* __restrict__ s1,
                                                  char* __restrict__ ws) {
  const int fl = *(const unsigned*)(ws + OFF_FLAG);
  int id = blockIdx.x * 256 + threadIdx.x;
  if (id < 65536) {
    int b = id >> 10, u = id & 1023;
    *(bf16*)(ws + OFF_H0PP + 131072 + hpack_off(b, u)) = (bf16)ldel(s0, b * 2048 + 1024 + u, fl);  // h0(-1) -> slot 1
  } else if (id < 131072) {
    int id2 = id - 65536; int b = id2 >> 10, u = id2 & 1023;
    *(bf16*)(ws + OFF_H1PP + hpack_off(b, u)) = (bf16)ldel(s1, b * 2048 + 1024 + u, fl);           // h1(-1) -> slot 0
  } else if (id < 131330) {
    ((unsigned*)(ws + OFF_FLAGS))[id - 131072] = 0u;   // 256 flags + release word
  }
}

// ---------------- persistent kernel: recurrence + fused output projection ----------------
// FINAL: exact R12 configuration (measured best: 4804 us; 3.04x vs session start).
// HYBRID coherence:
//   h STORES: sc0|sc1 write-through -> L3 always fresh, flag-after-vmcnt(0) ordering, NO wbl2.
//   h LOADS:  plain cached loads -> each XCD's L2 serves the 32-CU-shared h broadcast.
//   ACQUIRE:  buffer_inv only after the release poll — evicts stale h lines from L1/L2.
// Structure: 256 WGs x 256 threads, 4 waves, 1 WG/CU, 24-deep register ring, uniform
// outproj (2 MFMA/iter, 4-iter window), CU0-aggregate grid barrier with s_sleep(8).
// Session evidence: every attempt to add/reorder work around the barrier regressed
// (R4 -11%, R9 -3%, R11 -19%, R13 -28%); only removals of serial machinery won
// (R1 staging barriers -54%, R8 fence pair -21%, R10 load-path L2 reuse -4%).
__global__ __launch_bounds__(256, 1) void recur_kernel(const void* __restrict__ s0, const void* __restrict__ s1,
                                                       char* __restrict__ ws, void* __restrict__ outv) {
  extern __shared__ char smem[];
  const int fl = *(const unsigned*)(ws + OFF_FLAG);
  const int tid = threadIdx.x;
  const int lane = tid & 63;
  const int wid = tid >> 6;
  const int cu = blockIdx.x;
  const int nt = cu & 15, mo = (cu >> 4) & 3, dg = cu >> 6;

  auto store_out = [&](size_t idx, float v) {
    if (fl) ((float*)outv)[idx] = v; else ((bf16*)outv)[idx] = (bf16)v;
  };

  // ---- B preload (once) ----
  {
    const char* g0 = ws + OFF_W0P + (size_t)cu * 40960;
    for (int off = tid * 16; off < 40960; off += 4096) gl_lds16(smem + off, g0 + off);
    const char* g1 = ws + OFF_W1P + (size_t)cu * 65536;
    for (int off = tid * 16; off < 65536; off += 4096) gl_lds16(smem + 40960 + off, g1 + off);
  }
  // ---- Wout B-frags in registers ----
  bf16x8 wreg[8];
#pragma unroll
  for (int i = 0; i < 8; ++i)
    wreg[i] = *(const bf16x8*)(ws + OFF_WOUT + (size_t)(((wid * 8 + i) * 16 + nt) * 64 + lane) * 16);

  const float bini0 = ((const float*)(ws + OFF_B0P))[cu * 16 + (lane & 15)];
  const float bini1 = ((const float*)(ws + OFF_B1P))[cu * 16 + (lane & 15)];
  const float boN = ((const float*)(ws + OFF_BOP))[nt * 16 + (lane & 15)];
  const int u0 = cu * 4 + ((lane & 15) >> 2);
  float c0reg[4], c1reg[4];
#pragma unroll
  for (int r = 0; r < 4; ++r) {
    int b = wid * 16 + ((lane >> 4) << 2) + r;
    c0reg[r] = ldel(s0, b * 2048 + u0, fl);
    c1reg[r] = ldel(s1, b * 2048 + u0, fl);
  }

  const __amdgpu_buffer_rsrc_t rs = make_rsrc(ws);     // for write-through h stores only
  unsigned* flags = (unsigned*)(ws + OFF_FLAGS);
  unsigned* rel   = (unsigned*)(ws + OFF_REL);
  const char* dummy = ws + (size_t)lane * 16;          // always-valid bf16
  const char* lb0 = smem + (size_t)lane * 16;          // B0 frag base (+ s*1024 imm)
  const char* lb1 = smem + 40960 + (size_t)lane * 16;  // B1 frag base (+ (s-8)*1024 imm)

  __syncthreads();  // B preload landed

  // persistent outproj window state
  bf16x8 pf0, pf1, pf2, pf3, pf4, pf5, pf6, pf7;
  f32x4 accP;

  for (int it = 0; it < 517; ++it) {
    const bool a0 = (it < 512);
    const bool a1 = (it >= 1 && it <= 512);
    const bool last = (it == 516);
    const int p = (it - 2 - dg) & 3;
    const int tP = it - 2 - p;
    const bool pw = (it >= 2 && tP >= 0 && tP <= 511);
    const char* h0src = ws + OFF_H0PP + (size_t)((it + 1) & 1) * 131072;   // h0(it-1)
    const char* h1src = ws + OFF_H1PP + (size_t)((it + 1) & 1) * 131072;   // h1(it-2)

    const char* ph0 = (it <= 512) ? (h0src + (size_t)(wid * 32) * 1024 + (size_t)lane * 16) : dummy;
    const char* ph1 = a1 ? (h1src + (size_t)(wid * 32) * 1024 + (size_t)lane * 16) : dummy;

    // ---- p==0: load the window's 8 pf frags of h1(tP) into persistent regs (cached loads) ----
    if (pw && p == 0) {
      const char* pm = h1src + (size_t)(mo * 32 + wid * 8) * 1024 + (size_t)lane * 16;
      pf0 = *(const bf16x8*)(pm);
      pf1 = *(const bf16x8*)(pm + 1024);
      pf2 = *(const bf16x8*)(pm + 2048);
      pf3 = *(const bf16x8*)(pm + 3072);
      pf4 = *(const bf16x8*)(pm + 4096);
      pf5 = *(const bf16x8*)(pm + 5120);
      pf6 = *(const bf16x8*)(pm + 6144);
      pf7 = *(const bf16x8*)(pm + 7168);
#pragma unroll
      for (int r = 0; r < 4; ++r) accP[r] = 0.f;
    }

    f32x4 acc0, acc1;
#pragma unroll
    for (int r = 0; r < 4; ++r) { acc0[r] = bini0; acc1[r] = bini1; }

    if (it < 514) {
      const char* px = a0 ? (ws + OFF_XP + (size_t)((it * 4 + wid) * 8) * 1024 + (size_t)lane * 16) : dummy;

      // ---- register-ring streamed GEMM (24-deep, cached loads): 0..7=x, 8..39=h0, 40..71=h1 ----
      bf16x8 ring[24];
#pragma unroll
      for (int s = 0; s < 24; ++s)
        ring[s] = *(const bf16x8*)(s < 8 ? px + s * 1024 : ph0 + (s - 8) * 1024);
#pragma unroll
      for (int s = 0; s < 72; ++s) {
        bf16x8 af = ring[s % 24];
        const int f = s + 24;
        if (f < 72)
          ring[s % 24] = *(const bf16x8*)(f < 40 ? ph0 + (f - 8) * 1024 : ph1 + (f - 40) * 1024);
        if (s < 40)
          acc0 = __builtin_amdgcn_mfma_f32_16x16x32_bf16(af, *(const bf16x8*)(lb0 + s * 1024), acc0, 0, 0, 0);
        if (s >= 8)
          acc1 = __builtin_amdgcn_mfma_f32_16x16x32_bf16(af, *(const bf16x8*)(lb1 + (s - 8) * 1024), acc1, 0, 0, 0);
      }
    }

    // ---- 2 outproj MFMAs per iteration (uniform) ----
    if (pw) {
      switch (p) {
        case 0:
          accP = __builtin_amdgcn_mfma_f32_16x16x32_bf16(pf0, wreg[0], accP, 0, 0, 0);
          accP = __builtin_amdgcn_mfma_f32_16x16x32_bf16(pf1, wreg[1], accP, 0, 0, 0);
          break;
        case 1:
          accP = __builtin_amdgcn_mfma_f32_16x16x32_bf16(pf2, wreg[2], accP, 0, 0, 0);
          accP = __builtin_amdgcn_mfma_f32_16x16x32_bf16(pf3, wreg[3], accP, 0, 0, 0);
          break;
        case 2:
          accP = __builtin_amdgcn_mfma_f32_16x16x32_bf16(pf4, wreg[4], accP, 0, 0, 0);
          accP = __builtin_amdgcn_mfma_f32_16x16x32_bf16(pf5, wreg[5], accP, 0, 0, 0);
          break;
        default:
          accP = __builtin_amdgcn_mfma_f32_16x16x32_bf16(pf6, wreg[6], accP, 0, 0, 0);
          accP = __builtin_amdgcn_mfma_f32_16x16x32_bf16(pf7, wreg[7], accP, 0, 0, 0);
          break;
      }
    }

    // ---- LSTM epilogues (h stores: sc1 write-through) ----
    const int base = lane & 60;
    if (a0) {
      const unsigned h0w = (unsigned)(OFF_H0PP) + (unsigned)(it & 1) * 131072u;
#pragma unroll
      for (int r = 0; r < 4; ++r) {
        float z = acc0[r];
        float zi = scrub(__shfl(z, base + 0, 64), 80.f);
        float zj = scrub(__shfl(z, base + 1, 64), 80.f);
        float zf = scrub(__shfl(z, base + 2, 64), 80.f);
        float zo = scrub(__shfl(z, base + 3, 64), 80.f);
        float c = c0reg[r];
        c = c * sigm(zf + 1.0f) + sigm(zi) * tanh_(zj);
        c = scrub(c, 1000.f);
        float h = tanh_(c) * sigm(zo);
        c0reg[r] = c;
        if ((lane & 3) == 0) {
          int b = wid * 16 + ((lane >> 4) << 2) + r;
          st_h2(rs, h0w + (unsigned)hpack_off(b, u0), h);
          if (it == 511) { store_out(OUT_FS0 + b * 2048 + u0, c); store_out(OUT_FS0 + b * 2048 + 1024 + u0, h); }
        }
      }
    }
    if (a1) {
      const unsigned h1w = (unsigned)(OFF_H1PP) + (unsigned)(it & 1) * 131072u;
#pragma unroll
      for (int r = 0; r < 4; ++r) {
        float z = acc1[r];
        float zi = scrub(__shfl(z, base + 0, 64), 80.f);
        float zj = scrub(__shfl(z, base + 1, 64), 80.f);
        float zf = scrub(__shfl(z, base + 2, 64), 80.f);
        float zo = scrub(__shfl(z, base + 3, 64), 80.f);
        float c = c1reg[r];
        c = c * sigm(zf + 1.0f) + sigm(zi) * tanh_(zj);
        c = scrub(c, 1000.f);
        float h = tanh_(c) * sigm(zo);
        c1reg[r] = c;
        if ((lane & 3) == 0) {
          int b = wid * 16 + ((lane >> 4) << 2) + r;
          st_h2(rs, h1w + (unsigned)hpack_off(b, u0), h);
          if (it == 512) { store_out(OUT_FS1 + b * 2048 + u0, c); store_out(OUT_FS1 + b * 2048 + 1024 + u0, h); }
        }
      }
    }
    // ---- outproj finish (p==3): cross-wave reduce, write out[:, tP, nt-tile] ----
    if (pw && p == 3) {
      *(f32x4*)(smem + LDS_PARTP + (size_t)(wid * 64 + lane) * 16) = accP;
      __syncthreads();
      if (wid == 0) {
        f32x4 sm = *(const f32x4*)(smem + LDS_PARTP + (size_t)lane * 16);
#pragma unroll
        for (int w = 1; w < 4; ++w) {
          f32x4 q = *(const f32x4*)(smem + LDS_PARTP + (size_t)(w * 64 + lane) * 16);
#pragma unroll
          for (int r = 0; r < 4; ++r) sm[r] += q[r];
        }
#pragma unroll
        for (int r = 0; r < 4; ++r) {
          int b = mo * 16 + ((lane >> 4) << 2) + r;
          store_out(((size_t)b * 512 + tP) * 256 + nt * 16 + (lane & 15), sm[r] + boN);
        }
      }
    }
    if (last) break;

    // ---- barrier: drain write-through h stores -> arrive -> CU0 agg -> release -> inv ----
    asm volatile("s_waitcnt vmcnt(0)" ::: "memory");   // h stores ack'd at coherence point
    __syncthreads();
    if (tid == 0)
      __hip_atomic_store(flags + cu, (unsigned)(it + 1), __ATOMIC_RELAXED, __HIP_MEMORY_SCOPE_AGENT);
    if (cu == 0) {
      while (__hip_atomic_load(flags + tid, __ATOMIC_RELAXED, __HIP_MEMORY_SCOPE_AGENT) < (unsigned)(it + 1))
        __builtin_amdgcn_s_sleep(8);
      __syncthreads();
      if (tid == 0)
        __hip_atomic_store(rel, (unsigned)(it + 1), __ATOMIC_RELAXED, __HIP_MEMORY_SCOPE_AGENT);
    }
    if (tid == 0) {
      while (__hip_atomic_load(rel, __ATOMIC_RELAXED, __HIP_MEMORY_SCOPE_AGENT) < (unsigned)(it + 1))
        __builtin_amdgcn_s_sleep(8);
      __builtin_amdgcn_fence(__ATOMIC_ACQUIRE, "agent");   // inv L1/L2: evict stale h lines
    }
    __syncthreads();
  }
}

extern "C" void kernel_launch(void* const* d_in, const int* in_sizes, int n_in,
                              void* d_out, int out_size, void* d_ws, size_t ws_size,
                              hipStream_t stream) {
  const void* x    = d_in[0];
  const void* s0   = d_in[1];
  const void* s1   = d_in[2];
  const void* W0   = d_in[3];
  const void* b0   = d_in[4];
  const void* W1   = d_in[5];
  const void* b1   = d_in[6];
  const void* Wout = d_in[7];
  const void* bout = d_in[8];
  char* ws = (char*)d_ws;
  (void)in_sizes; (void)n_in; (void)out_size; (void)ws_size;

  hipFuncSetAttribute((const void*)recur_kernel, hipFuncAttributeMaxDynamicSharedMemorySize, LDS_TOTAL);

  hipLaunchKernelGGL(detect_kernel, dim3(1),     dim3(256), 0, stream, W0, ws);
  hipLaunchKernelGGL(prep_pack,     dim3(87073), dim3(256), 0, stream, x, W0, b0, W1, b1, Wout, bout, ws);
  hipLaunchKernelGGL(init_state,    dim3(514),   dim3(256), 0, stream, s0, s1, ws);
  hipLaunchKernelGGL(recur_kernel,  dim3(256),   dim3(256), LDS_TOTAL, stream, s0, s1, ws, d_out);
}